// Round 1
// baseline (438.918 us; speedup 1.0000x reference)
//
#include <hip/hip_runtime.h>

// 3-layer SplineConv (kernel 3x3, degree 2, open spline).
// Strategy: per layer,
//   (1) transform_kernel: y[n, k*32+c] = sum_i X[n,i] * W[k,i,c]  (k=0..8)
//                         agg[n,c]     = sum_i X[n,i] * root[i,c] + bias[c]
//   (2) edge_kernel: per edge e, msg[c] = sum_{a,b} q1_a q0_b y[src, (3a+b)*32+c],
//                    atomicAdd into agg[dst, c].
// Layer chain: L1(x,W1) -> relu -> concat(skip) -> L2(W1) -> relu -> L3(W2) -> relu.

#define TN 64  // nodes per transform block

template<int CIN, int MODE>
__global__ __launch_bounds__(256)
void transform_kernel(const float* __restrict__ Xa, const float* __restrict__ Xb,
                      const float* __restrict__ W, const float* __restrict__ root,
                      const float* __restrict__ bias,
                      float* __restrict__ y, float* __restrict__ agg, int N)
{
    // MODE 0: X = Xa [N,CIN] plain
    // MODE 1: X[n,i] = i<32 ? relu(Xa[n,i]) : Xb[n,i-32]   (CIN=64)
    // MODE 2: X = relu(Xa) [N,CIN]
    __shared__ float sX[TN][CIN + 1];
    const int t = threadIdx.x;
    const int base = blockIdx.x * TN;

    // Stage X tile (coalesced)
    const int TOT = TN * CIN;
    for (int idx = t; idx < TOT; idx += 256) {
        int nl = idx / CIN;
        int i  = idx % CIN;
        int n  = base + nl;
        float v = 0.f;
        if (n < N) {
            if (MODE == 0)      v = Xa[(size_t)n * CIN + i];
            else if (MODE == 1) v = (i < 32) ? fmaxf(Xa[(size_t)n * 32 + i], 0.f)
                                             : Xb[(size_t)n * 32 + (i - 32)];
            else                v = fmaxf(Xa[(size_t)n * CIN + i], 0.f);
        }
        sX[nl][i] = v;
    }
    __syncthreads();

    const int c = t & 31;   // output channel
    const int q = t >> 5;   // node group 0..7, each handles 8 nodes

    float acc[8][10];
    #pragma unroll
    for (int j = 0; j < 8; ++j)
        #pragma unroll
        for (int k = 0; k < 10; ++k) acc[j][k] = 0.f;

    for (int i = 0; i < CIN; ++i) {
        float wv[10];
        #pragma unroll
        for (int k = 0; k < 9; ++k)
            wv[k] = W[((size_t)k * CIN + i) * 32 + c];
        wv[9] = root[(size_t)i * 32 + c];
        #pragma unroll
        for (int j = 0; j < 8; ++j) {
            float xv = sX[q * 8 + j][i];
            #pragma unroll
            for (int k = 0; k < 10; ++k)
                acc[j][k] = fmaf(xv, wv[k], acc[j][k]);
        }
    }

    float bv = bias[c];
    #pragma unroll
    for (int j = 0; j < 8; ++j) {
        int n = base + q * 8 + j;
        if (n < N) {
            #pragma unroll
            for (int k = 0; k < 9; ++k)
                y[(size_t)n * 288 + k * 32 + c] = acc[j][k];
            agg[(size_t)n * 32 + c] = acc[j][9] + bv;
        }
    }
}

__global__ __launch_bounds__(256)
void edge_kernel(const int* __restrict__ ei, const float* __restrict__ pseudo,
                 const float* __restrict__ y, float* __restrict__ agg, int E)
{
    const int t = threadIdx.x;
    const int e = blockIdx.x * 8 + (t >> 5);
    if (e >= E) return;
    const int c = t & 31;

    const int src = ei[e];
    const int dst = ei[E + e];
    const float p0 = pseudo[2 * (size_t)e];
    const float p1 = pseudo[2 * (size_t)e + 1];

    // open B-spline basis, degree 2
    const float q00 = 0.5f * (1.f - p0) * (1.f - p0);
    const float q01 = -p0 * p0 + p0 + 0.5f;
    const float q02 = 0.5f * p0 * p0;
    const float q10 = 0.5f * (1.f - p1) * (1.f - p1);
    const float q11 = -p1 * p1 + p1 + 0.5f;
    const float q12 = 0.5f * p1 * p1;

    const float* yb = y + (size_t)src * 288 + c;
    float m0 = q00 * yb[0]   + q01 * yb[32]  + q02 * yb[64];
    float m1 = q00 * yb[96]  + q01 * yb[128] + q02 * yb[160];
    float m2 = q00 * yb[192] + q01 * yb[224] + q02 * yb[256];
    float msg = q10 * m0 + q11 * m1 + q12 * m2;

    atomicAdd(agg + (size_t)dst * 32 + c, msg);
}

__global__ __launch_bounds__(1024)
void relu_kernel(float* __restrict__ p, int n)
{
    int i = blockIdx.x * 1024 + threadIdx.x;
    if (i < n) p[i] = fmaxf(p[i], 0.f);
}

extern "C" void kernel_launch(void* const* d_in, const int* in_sizes, int n_in,
                              void* d_out, int out_size, void* d_ws, size_t ws_size,
                              hipStream_t stream) {
    const float* x      = (const float*)d_in[0];
    const int*   ei     = (const int*)  d_in[1];
    const float* pseudo = (const float*)d_in[2];
    const float* skip   = (const float*)d_in[3];
    const float* W1     = (const float*)d_in[4];
    const float* root1  = (const float*)d_in[5];
    const float* b1     = (const float*)d_in[6];
    const float* W2     = (const float*)d_in[7];
    const float* root2  = (const float*)d_in[8];
    const float* b2     = (const float*)d_in[9];

    const int N = in_sizes[0] / 64;
    const int E = in_sizes[1] / 2;
    float* out = (float*)d_out;

    float* ws   = (float*)d_ws;
    float* y    = ws;                          // N*288
    float* agg1 = y + (size_t)N * 288;         // N*32
    float* agg2 = agg1 + (size_t)N * 32;       // N*32

    const dim3 blk(256);
    const int tb = (N + TN - 1) / TN;
    const int eb = (E + 7) / 8;

    // Layer 1
    transform_kernel<64, 0><<<tb, blk, 0, stream>>>(x, nullptr, W1, root1, b1, y, agg1, N);
    edge_kernel<<<eb, blk, 0, stream>>>(ei, pseudo, y, agg1, E);
    // Layer 2 (input = concat(relu(agg1), skip), same weights W1)
    transform_kernel<64, 1><<<tb, blk, 0, stream>>>(agg1, skip, W1, root1, b1, y, agg2, N);
    edge_kernel<<<eb, blk, 0, stream>>>(ei, pseudo, y, agg2, E);
    // Layer 3 (input = relu(agg2), weights W2), agg straight into d_out
    transform_kernel<32, 2><<<tb, blk, 0, stream>>>(agg2, nullptr, W2, root2, b2, y, out, N);
    edge_kernel<<<eb, blk, 0, stream>>>(ei, pseudo, y, out, E);
    // Final relu in place
    relu_kernel<<<(N * 32 + 1023) / 1024, 1024, 0, stream>>>(out, N * 32);
}

// Round 2
// 427.397 us; speedup vs baseline: 1.0270x; 1.0270x over previous
//
#include <hip/hip_runtime.h>

// 3-layer SplineConv (kernel 3x3, degree 2, open spline).
// Per layer:
//   (1) transform_kernel: y[n, k*32+c] = sum_i X[n,i] * W[k,i,c]  (k=0..8)
//                         agg[n,c]     = sum_i X[n,i] * root[i,c] + bias[c]
//   (2) edge_sorted: per edge e (sorted by src), msg[c] = sum_{a,b} q1_a q0_b y[src,(3a+b)*32+c],
//       atomicAdd into agg[dst,c].  Sorting by src makes the 1152 B/edge y-gather L1/L2-local.
// Edge order (counting sort by src) computed once, reused by all 3 layers.

#define TN 64  // nodes per transform block

template<int CIN, int MODE>
__global__ __launch_bounds__(256)
void transform_kernel(const float* __restrict__ Xa, const float* __restrict__ Xb,
                      const float* __restrict__ W, const float* __restrict__ root,
                      const float* __restrict__ bias,
                      float* __restrict__ y, float* __restrict__ agg, int N)
{
    // MODE 0: X = Xa [N,CIN] plain
    // MODE 1: X[n,i] = i<32 ? relu(Xa[n,i]) : Xb[n,i-32]   (CIN=64); agg may alias Xa (in-place)
    // MODE 2: X = relu(Xa) [N,CIN]
    __shared__ float sX[TN][CIN + 1];
    const int t = threadIdx.x;
    const int base = blockIdx.x * TN;

    const int TOT = TN * CIN;
    for (int idx = t; idx < TOT; idx += 256) {
        int nl = idx / CIN;
        int i  = idx % CIN;
        int n  = base + nl;
        float v = 0.f;
        if (n < N) {
            if (MODE == 0)      v = Xa[(size_t)n * CIN + i];
            else if (MODE == 1) v = (i < 32) ? fmaxf(Xa[(size_t)n * 32 + i], 0.f)
                                             : Xb[(size_t)n * 32 + (i - 32)];
            else                v = fmaxf(Xa[(size_t)n * CIN + i], 0.f);
        }
        sX[nl][i] = v;
    }
    __syncthreads();

    const int c = t & 31;   // output channel
    const int q = t >> 5;   // node group 0..7, each handles 8 nodes

    float acc[8][10];
    #pragma unroll
    for (int j = 0; j < 8; ++j)
        #pragma unroll
        for (int k = 0; k < 10; ++k) acc[j][k] = 0.f;

    for (int i = 0; i < CIN; ++i) {
        float wv[10];
        #pragma unroll
        for (int k = 0; k < 9; ++k)
            wv[k] = W[((size_t)k * CIN + i) * 32 + c];
        wv[9] = root[(size_t)i * 32 + c];
        #pragma unroll
        for (int j = 0; j < 8; ++j) {
            float xv = sX[q * 8 + j][i];
            #pragma unroll
            for (int k = 0; k < 10; ++k)
                acc[j][k] = fmaf(xv, wv[k], acc[j][k]);
        }
    }

    float bv = bias[c];
    #pragma unroll
    for (int j = 0; j < 8; ++j) {
        int n = base + q * 8 + j;
        if (n < N) {
            #pragma unroll
            for (int k = 0; k < 9; ++k)
                y[(size_t)n * 288 + k * 32 + c] = acc[j][k];
            agg[(size_t)n * 32 + c] = acc[j][9] + bv;
        }
    }
}

// ---------- edge-order prep: counting sort by src ----------

__global__ __launch_bounds__(1024)
void zero_kernel(int* __restrict__ p, int n)
{
    int i = blockIdx.x * 1024 + threadIdx.x;
    if (i < n) p[i] = 0;
}

__global__ __launch_bounds__(256)
void count_kernel(const int* __restrict__ ei, int* __restrict__ hist, int E)
{
    int e = blockIdx.x * 256 + threadIdx.x;
    if (e < E) atomicAdd(&hist[ei[e]], 1);
}

// in-place: hist[i] -> exclusive scan within block; bsum[b] = block total
__global__ __launch_bounds__(1024)
void scan1_kernel(int* __restrict__ hist, int* __restrict__ bsum, int n)
{
    __shared__ int s[1024];
    int tid = threadIdx.x;
    int i = blockIdx.x * 1024 + tid;
    int v = (i < n) ? hist[i] : 0;
    s[tid] = v;
    __syncthreads();
    for (int off = 1; off < 1024; off <<= 1) {
        int add = (tid >= off) ? s[tid - off] : 0;
        __syncthreads();
        s[tid] += add;
        __syncthreads();
    }
    if (i < n) hist[i] = s[tid] - v;          // exclusive within block
    if (tid == 1023) bsum[blockIdx.x] = s[1023];
}

// single block: exclusive scan of bsum (nb <= 256)
__global__ __launch_bounds__(256)
void scan2_kernel(int* __restrict__ bsum, int nb)
{
    __shared__ int s[256];
    int tid = threadIdx.x;
    int v = (tid < nb) ? bsum[tid] : 0;
    s[tid] = v;
    __syncthreads();
    for (int off = 1; off < 256; off <<= 1) {
        int add = (tid >= off) ? s[tid - off] : 0;
        __syncthreads();
        s[tid] += add;
        __syncthreads();
    }
    if (tid < nb) bsum[tid] = s[tid] - v;     // exclusive
}

__global__ __launch_bounds__(1024)
void scan3_kernel(int* __restrict__ hist, const int* __restrict__ bsum, int n)
{
    int i = blockIdx.x * 1024 + threadIdx.x;
    if (i < n) hist[i] += bsum[blockIdx.x];
}

// place each edge at pos = start[src]++, writing sorted src/dst/pseudo
__global__ __launch_bounds__(256)
void scatter_kernel(const int* __restrict__ ei, const float* __restrict__ pseudo,
                    int* __restrict__ start,
                    int* __restrict__ s_src, int* __restrict__ s_dst,
                    float* __restrict__ s_pp, int E)
{
    int e = blockIdx.x * 256 + threadIdx.x;
    if (e >= E) return;
    int s = ei[e];
    int d = ei[E + e];
    float p0 = pseudo[2 * (size_t)e];
    float p1 = pseudo[2 * (size_t)e + 1];
    int pos = atomicAdd(&start[s], 1);
    s_src[pos] = s;
    s_dst[pos] = d;
    s_pp[2 * (size_t)pos]     = p0;
    s_pp[2 * (size_t)pos + 1] = p1;
}

// ---------- edge kernel over sorted edges ----------

__global__ __launch_bounds__(256)
void edge_sorted(const int* __restrict__ s_src, const int* __restrict__ s_dst,
                 const float* __restrict__ s_pp,
                 const float* __restrict__ y, float* __restrict__ agg, int E)
{
    const int t = threadIdx.x;
    const int e = blockIdx.x * 8 + (t >> 5);
    if (e >= E) return;
    const int c = t & 31;

    const int src = s_src[e];
    const int dst = s_dst[e];
    const float p0 = s_pp[2 * (size_t)e];
    const float p1 = s_pp[2 * (size_t)e + 1];

    const float q00 = 0.5f * (1.f - p0) * (1.f - p0);
    const float q01 = -p0 * p0 + p0 + 0.5f;
    const float q02 = 0.5f * p0 * p0;
    const float q10 = 0.5f * (1.f - p1) * (1.f - p1);
    const float q11 = -p1 * p1 + p1 + 0.5f;
    const float q12 = 0.5f * p1 * p1;

    const float* yb = y + (size_t)src * 288 + c;
    float m0 = q00 * yb[0]   + q01 * yb[32]  + q02 * yb[64];
    float m1 = q00 * yb[96]  + q01 * yb[128] + q02 * yb[160];
    float m2 = q00 * yb[192] + q01 * yb[224] + q02 * yb[256];
    float msg = q10 * m0 + q11 * m1 + q12 * m2;

    atomicAdd(agg + (size_t)dst * 32 + c, msg);
}

__global__ __launch_bounds__(1024)
void relu_kernel(float* __restrict__ p, int n)
{
    int i = blockIdx.x * 1024 + threadIdx.x;
    if (i < n) p[i] = fmaxf(p[i], 0.f);
}

extern "C" void kernel_launch(void* const* d_in, const int* in_sizes, int n_in,
                              void* d_out, int out_size, void* d_ws, size_t ws_size,
                              hipStream_t stream) {
    const float* x      = (const float*)d_in[0];
    const int*   ei     = (const int*)  d_in[1];
    const float* pseudo = (const float*)d_in[2];
    const float* skip   = (const float*)d_in[3];
    const float* W1     = (const float*)d_in[4];
    const float* root1  = (const float*)d_in[5];
    const float* b1     = (const float*)d_in[6];
    const float* W2     = (const float*)d_in[7];
    const float* root2  = (const float*)d_in[8];
    const float* b2     = (const float*)d_in[9];

    const int N = in_sizes[0] / 64;
    const int E = in_sizes[1] / 2;
    float* out = (float*)d_out;

    // ws layout (total == N*320*4 + E*16 == 70.4 MB for N=50000, E=400000):
    float* ws    = (float*)d_ws;
    float* y     = ws;                          // N*288 floats
    float* agg1  = y + (size_t)N * 288;         // N*32 floats
    int*   s_src = (int*)(agg1 + (size_t)N * 32);   // E ints
    int*   s_dst = s_src + E;                   // E ints
    float* s_pp  = (float*)(s_dst + E);         // E*2 floats
    // scan scratch aliases y (dead during prep, overwritten by transform1 after)
    int*   start = (int*)y;                     // N ints
    int*   bsum  = start + N;                   // <=256 ints

    const dim3 blk(256);
    const int tb  = (N + TN - 1) / TN;
    const int eb  = (E + 7) / 8;
    const int e256 = (E + 255) / 256;
    const int n1k  = (N + 1023) / 1024;

    // ---- prep: counting sort of edges by src (reused by all 3 layers) ----
    zero_kernel<<<n1k, 1024, 0, stream>>>(start, N);
    count_kernel<<<e256, blk, 0, stream>>>(ei, start, E);
    scan1_kernel<<<n1k, 1024, 0, stream>>>(start, bsum, N);
    scan2_kernel<<<1, 256, 0, stream>>>(bsum, n1k);
    scan3_kernel<<<n1k, 1024, 0, stream>>>(start, bsum, N);
    scatter_kernel<<<e256, blk, 0, stream>>>(ei, pseudo, start, s_src, s_dst, s_pp, E);

    // ---- Layer 1 ----
    transform_kernel<64, 0><<<tb, blk, 0, stream>>>(x, nullptr, W1, root1, b1, y, agg1, N);
    edge_sorted<<<eb, blk, 0, stream>>>(s_src, s_dst, s_pp, y, agg1, E);
    // ---- Layer 2 (input = concat(relu(agg1), skip), same W1); agg in-place over agg1 ----
    transform_kernel<64, 1><<<tb, blk, 0, stream>>>(agg1, skip, W1, root1, b1, y, agg1, N);
    edge_sorted<<<eb, blk, 0, stream>>>(s_src, s_dst, s_pp, y, agg1, E);
    // ---- Layer 3 (input = relu(agg1), W2), agg straight into d_out ----
    transform_kernel<32, 2><<<tb, blk, 0, stream>>>(agg1, nullptr, W2, root2, b2, y, out, N);
    edge_sorted<<<eb, blk, 0, stream>>>(s_src, s_dst, s_pp, y, out, E);
    relu_kernel<<<(N * 32 + 1023) / 1024, 1024, 0, stream>>>(out, N * 32);
}